// Round 4
// baseline (577.597 us; speedup 1.0000x reference)
//
#include <hip/hip_runtime.h>

#define NROWS 16384
#define DIM   1024          // floats per row
#define MARGIN_F 1.0f
#define EPS_F 1e-6f
#define NBLOCKS (NROWS / 4)
#define NSLOTS 64

// Fully fused: one WAVE per row (4 rows / 256-thread block).
// Per wave: 12 coalesced float4 loads (a,b,c rows), 5 interleaved FMA chains
// (|a|^2,|b|^2,|c|^2, a.b, a.c), ONE 6-step butterfly over all 5 values, then
//   d^2 = |u-v|^2 = 2 - 2*si*sj*(a.b)   (unit-norm cross term; eps terms ~2e-6)
// Reduction: per-wave atomicAdd into 64 spread slots; last block (atomic done
// counter) sums the slots and writes the scalar. No second big kernel, no
// losses[] round-trip, no intra-block barriers on the hot path.
__global__ __launch_bounds__(256) void row_loss_kernel(
    const float* __restrict__ emb,
    const int*   __restrict__ pos_idx,
    const int*   __restrict__ neg_idx,
    float*        __restrict__ acc,     // [NSLOTS] zeroed
    unsigned int* __restrict__ done,    // [1] zeroed
    float*        __restrict__ out)
{
    const int tid  = threadIdx.x;
    const int lane = tid & 63;
    const int wid  = tid >> 6;
    const int row  = blockIdx.x * 4 + wid;

    const int p = pos_idx[row];
    const int n = neg_idx[row];

    const float4* xi = (const float4*)(emb + (size_t)row * DIM);
    const float4* xp = (const float4*)(emb + (size_t)p   * DIM);
    const float4* xn = (const float4*)(emb + (size_t)n   * DIM);

    float4 a[4], b[4], c[4];
    #pragma unroll
    for (int j = 0; j < 4; ++j) {
        a[j] = xi[lane + 64 * j];
        b[j] = xp[lane + 64 * j];
        c[j] = xn[lane + 64 * j];
    }

    // 5 interleaved reduction chains
    float ni = 0.f, np_ = 0.f, nn = 0.f, dab = 0.f, dac = 0.f;
    #pragma unroll
    for (int j = 0; j < 4; ++j) {
        ni  = fmaf(a[j].x, a[j].x, ni);  ni  = fmaf(a[j].y, a[j].y, ni);
        ni  = fmaf(a[j].z, a[j].z, ni);  ni  = fmaf(a[j].w, a[j].w, ni);
        np_ = fmaf(b[j].x, b[j].x, np_); np_ = fmaf(b[j].y, b[j].y, np_);
        np_ = fmaf(b[j].z, b[j].z, np_); np_ = fmaf(b[j].w, b[j].w, np_);
        nn  = fmaf(c[j].x, c[j].x, nn);  nn  = fmaf(c[j].y, c[j].y, nn);
        nn  = fmaf(c[j].z, c[j].z, nn);  nn  = fmaf(c[j].w, c[j].w, nn);
        dab = fmaf(a[j].x, b[j].x, dab); dab = fmaf(a[j].y, b[j].y, dab);
        dab = fmaf(a[j].z, b[j].z, dab); dab = fmaf(a[j].w, b[j].w, dab);
        dac = fmaf(a[j].x, c[j].x, dac); dac = fmaf(a[j].y, c[j].y, dac);
        dac = fmaf(a[j].z, c[j].z, dac); dac = fmaf(a[j].w, c[j].w, dac);
    }
    // single butterfly phase over all 5 values
    #pragma unroll
    for (int m = 1; m < 64; m <<= 1) {
        ni  += __shfl_xor(ni,  m, 64);
        np_ += __shfl_xor(np_, m, 64);
        nn  += __shfl_xor(nn,  m, 64);
        dab += __shfl_xor(dab, m, 64);
        dac += __shfl_xor(dac, m, 64);
    }

    if (lane == 0) {
        const float si = 1.0f / fmaxf(sqrtf(ni),  EPS_F);
        const float sp = 1.0f / fmaxf(sqrtf(np_), EPS_F);
        const float sn = 1.0f / fmaxf(sqrtf(nn),  EPS_F);
        float sum_p = fmaxf(2.0f - 2.0f * si * sp * dab, 0.0f);
        float sum_n = fmaxf(2.0f - 2.0f * si * sn * dac, 0.0f);
        float d_pos = sqrtf(sum_p) + EPS_F;
        float d_neg = sqrtf(sum_n) + EPS_F;
        float mq = fmaxf(MARGIN_F - d_neg, EPS_F);
        float loss = d_pos * d_pos + mq * mq;
        atomicAdd(&acc[blockIdx.x & (NSLOTS - 1)], loss);
    }

    // ---- last-block-done finalize ----
    __threadfence();            // order the acc atomic before the done signal
    __syncthreads();            // all 4 waves' atomics fenced

    __shared__ int is_last;
    if (tid == 0) {
        unsigned int old = atomicAdd(done, 1u);
        is_last = (old == (unsigned int)(NBLOCKS - 1));
    }
    __syncthreads();

    if (is_last && wid == 0) {
        // agent-scope atomic load: bypass possibly-stale local L1/L2 copies
        float v = __hip_atomic_load(&acc[lane], __ATOMIC_RELAXED,
                                    __HIP_MEMORY_SCOPE_AGENT);
        #pragma unroll
        for (int m = 1; m < 64; m <<= 1) v += __shfl_xor(v, m, 64);
        if (lane == 0) out[0] = v / (2.0f * (float)NROWS);
    }
}

extern "C" void kernel_launch(void* const* d_in, const int* in_sizes, int n_in,
                              void* d_out, int out_size, void* d_ws, size_t ws_size,
                              hipStream_t stream) {
    const float* emb = (const float*)d_in[0];
    // d_in[1] = labels (unused by the loss itself)
    const int* pos = (const int*)d_in[2];
    const int* neg = (const int*)d_in[3];

    float*        acc  = (float*)d_ws;                    // 64 floats
    unsigned int* done = (unsigned int*)((char*)d_ws + NSLOTS * sizeof(float));
    float*        out  = (float*)d_out;

    hipMemsetAsync(d_ws, 0, 512, stream);                 // zero acc + done
    row_loss_kernel<<<NBLOCKS, 256, 0, stream>>>(emb, pos, neg, acc, done, out);
}

// Round 5
// 112.798 us; speedup vs baseline: 5.1206x; 5.1206x over previous
//
#include <hip/hip_runtime.h>

#define NROWS 16384
#define DIM   1024          // floats per row
#define MARGIN_F 1.0f
#define EPS_F 1e-6f

// One WAVE per row (4 rows per 256-thread block). 12 coalesced float4 loads,
// 5 interleaved FMA chains (|a|^2,|b|^2,|c|^2,a.b,a.c), ONE 6-step butterfly,
// then d^2 = 2 - 2*si*sj*dot (unit-norm algebra; eps cross-terms ~2e-6).
// NO atomics (R4 showed cross-XCD same-line atomicAdd serialization cost
// ~450 us). Per-row loss goes to d_ws; tiny kernel 2 reduces it.
__global__ __launch_bounds__(256) void row_loss_kernel(
    const float* __restrict__ emb,
    const int*   __restrict__ pos_idx,
    const int*   __restrict__ neg_idx,
    float*       __restrict__ losses)
{
    const int tid  = threadIdx.x;
    const int lane = tid & 63;
    const int wid  = tid >> 6;
    const int row  = blockIdx.x * 4 + wid;

    const int p = pos_idx[row];
    const int n = neg_idx[row];

    const float4* xi = (const float4*)(emb + (size_t)row * DIM);
    const float4* xp = (const float4*)(emb + (size_t)p   * DIM);
    const float4* xn = (const float4*)(emb + (size_t)n   * DIM);

    float4 a[4], b[4], c[4];
    #pragma unroll
    for (int j = 0; j < 4; ++j) {
        a[j] = xi[lane + 64 * j];
        b[j] = xp[lane + 64 * j];
        c[j] = xn[lane + 64 * j];
    }

    // 5 interleaved reduction chains
    float ni = 0.f, np_ = 0.f, nn = 0.f, dab = 0.f, dac = 0.f;
    #pragma unroll
    for (int j = 0; j < 4; ++j) {
        ni  = fmaf(a[j].x, a[j].x, ni);  ni  = fmaf(a[j].y, a[j].y, ni);
        ni  = fmaf(a[j].z, a[j].z, ni);  ni  = fmaf(a[j].w, a[j].w, ni);
        np_ = fmaf(b[j].x, b[j].x, np_); np_ = fmaf(b[j].y, b[j].y, np_);
        np_ = fmaf(b[j].z, b[j].z, np_); np_ = fmaf(b[j].w, b[j].w, np_);
        nn  = fmaf(c[j].x, c[j].x, nn);  nn  = fmaf(c[j].y, c[j].y, nn);
        nn  = fmaf(c[j].z, c[j].z, nn);  nn  = fmaf(c[j].w, c[j].w, nn);
        dab = fmaf(a[j].x, b[j].x, dab); dab = fmaf(a[j].y, b[j].y, dab);
        dab = fmaf(a[j].z, b[j].z, dab); dab = fmaf(a[j].w, b[j].w, dab);
        dac = fmaf(a[j].x, c[j].x, dac); dac = fmaf(a[j].y, c[j].y, dac);
        dac = fmaf(a[j].z, c[j].z, dac); dac = fmaf(a[j].w, c[j].w, dac);
    }
    // single butterfly phase over all 5 values
    #pragma unroll
    for (int m = 1; m < 64; m <<= 1) {
        ni  += __shfl_xor(ni,  m, 64);
        np_ += __shfl_xor(np_, m, 64);
        nn  += __shfl_xor(nn,  m, 64);
        dab += __shfl_xor(dab, m, 64);
        dac += __shfl_xor(dac, m, 64);
    }

    if (lane == 0) {
        const float si = 1.0f / fmaxf(sqrtf(ni),  EPS_F);
        const float sp = 1.0f / fmaxf(sqrtf(np_), EPS_F);
        const float sn = 1.0f / fmaxf(sqrtf(nn),  EPS_F);
        float sum_p = fmaxf(2.0f - 2.0f * si * sp * dab, 0.0f);
        float sum_n = fmaxf(2.0f - 2.0f * si * sn * dac, 0.0f);
        float d_pos = sqrtf(sum_p) + EPS_F;
        float d_neg = sqrtf(sum_n) + EPS_F;
        float mq = fmaxf(MARGIN_F - d_neg, EPS_F);
        losses[row] = d_pos * d_pos + mq * mq;
    }
}

__global__ __launch_bounds__(1024) void final_reduce_kernel(
    const float* __restrict__ losses,
    float*       __restrict__ out)
{
    const int tid  = threadIdx.x;
    const int lane = tid & 63;
    const int wid  = tid >> 6;   // 16 waves

    const float4* l4 = (const float4*)losses;   // NROWS/4 = 4096 float4
    float s = 0.0f;
    #pragma unroll
    for (int j = 0; j < 4; ++j) {
        float4 v = l4[tid + 1024 * j];
        s += v.x + v.y + v.z + v.w;
    }
    #pragma unroll
    for (int m = 1; m < 64; m <<= 1) s += __shfl_xor(s, m, 64);

    __shared__ float sm[16];
    if (lane == 0) sm[wid] = s;
    __syncthreads();
    if (tid == 0) {
        float total = 0.f;
        #pragma unroll
        for (int w = 0; w < 16; ++w) total += sm[w];
        out[0] = total / (2.0f * (float)NROWS);
    }
}

extern "C" void kernel_launch(void* const* d_in, const int* in_sizes, int n_in,
                              void* d_out, int out_size, void* d_ws, size_t ws_size,
                              hipStream_t stream) {
    const float* emb = (const float*)d_in[0];
    // d_in[1] = labels (unused by the loss itself)
    const int* pos = (const int*)d_in[2];
    const int* neg = (const int*)d_in[3];

    float* losses = (float*)d_ws;          // NROWS floats of scratch
    float* out    = (float*)d_out;

    row_loss_kernel<<<NROWS / 4, 256, 0, stream>>>(emb, pos, neg, losses);
    final_reduce_kernel<<<1, 1024, 0, stream>>>(losses, out);
}

// Round 6
// 112.083 us; speedup vs baseline: 5.1533x; 1.0064x over previous
//
#include <hip/hip_runtime.h>

#define NROWS 16384
#define DIM   1024          // floats per row
#define MARGIN_F 1.0f
#define EPS_F 1e-6f

// One WAVE per row (4 rows per 256-thread block).
// KEY CHANGE vs R5: an asm memory barrier between the load loop and the
// compute loop. R4's counter CSV showed VGPR_Count=32 — impossible if all
// 12 float4 gathers (48 VGPRs of data) were in flight; the compiler was
// sinking loads into the FMA loop, serializing ~4 HBM-miss rounds per wave.
// The barrier forces all 12 loads to issue first (one miss round).
__global__ __launch_bounds__(256) void row_loss_kernel(
    const float* __restrict__ emb,
    const int*   __restrict__ pos_idx,
    const int*   __restrict__ neg_idx,
    float*       __restrict__ losses)
{
    const int tid  = threadIdx.x;
    const int lane = tid & 63;
    const int wid  = tid >> 6;
    const int row  = blockIdx.x * 4 + wid;

    const int p = pos_idx[row];
    const int n = neg_idx[row];

    const float4* xi = (const float4*)(emb + (size_t)row * DIM);
    const float4* xp = (const float4*)(emb + (size_t)p   * DIM);
    const float4* xn = (const float4*)(emb + (size_t)n   * DIM);

    float4 a[4], b[4], c[4];
    #pragma unroll
    for (int j = 0; j < 4; ++j) {
        a[j] = xi[lane + 64 * j];
        b[j] = xp[lane + 64 * j];
        c[j] = xn[lane + 64 * j];
    }
    // Do not let the compiler sink any of the 12 loads into the compute loop.
    asm volatile("" ::: "memory");

    // 5 interleaved reduction chains
    float ni = 0.f, np_ = 0.f, nn = 0.f, dab = 0.f, dac = 0.f;
    #pragma unroll
    for (int j = 0; j < 4; ++j) {
        ni  = fmaf(a[j].x, a[j].x, ni);  ni  = fmaf(a[j].y, a[j].y, ni);
        ni  = fmaf(a[j].z, a[j].z, ni);  ni  = fmaf(a[j].w, a[j].w, ni);
        np_ = fmaf(b[j].x, b[j].x, np_); np_ = fmaf(b[j].y, b[j].y, np_);
        np_ = fmaf(b[j].z, b[j].z, np_); np_ = fmaf(b[j].w, b[j].w, np_);
        nn  = fmaf(c[j].x, c[j].x, nn);  nn  = fmaf(c[j].y, c[j].y, nn);
        nn  = fmaf(c[j].z, c[j].z, nn);  nn  = fmaf(c[j].w, c[j].w, nn);
        dab = fmaf(a[j].x, b[j].x, dab); dab = fmaf(a[j].y, b[j].y, dab);
        dab = fmaf(a[j].z, b[j].z, dab); dab = fmaf(a[j].w, b[j].w, dab);
        dac = fmaf(a[j].x, c[j].x, dac); dac = fmaf(a[j].y, c[j].y, dac);
        dac = fmaf(a[j].z, c[j].z, dac); dac = fmaf(a[j].w, c[j].w, dac);
    }
    // single butterfly phase over all 5 values
    #pragma unroll
    for (int m = 1; m < 64; m <<= 1) {
        ni  += __shfl_xor(ni,  m, 64);
        np_ += __shfl_xor(np_, m, 64);
        nn  += __shfl_xor(nn,  m, 64);
        dab += __shfl_xor(dab, m, 64);
        dac += __shfl_xor(dac, m, 64);
    }

    if (lane == 0) {
        const float si = 1.0f / fmaxf(sqrtf(ni),  EPS_F);
        const float sp = 1.0f / fmaxf(sqrtf(np_), EPS_F);
        const float sn = 1.0f / fmaxf(sqrtf(nn),  EPS_F);
        float sum_p = fmaxf(2.0f - 2.0f * si * sp * dab, 0.0f);
        float sum_n = fmaxf(2.0f - 2.0f * si * sn * dac, 0.0f);
        float d_pos = sqrtf(sum_p) + EPS_F;
        float d_neg = sqrtf(sum_n) + EPS_F;
        float mq = fmaxf(MARGIN_F - d_neg, EPS_F);
        losses[row] = d_pos * d_pos + mq * mq;
    }
}

__global__ __launch_bounds__(1024) void final_reduce_kernel(
    const float* __restrict__ losses,
    float*       __restrict__ out)
{
    const int tid  = threadIdx.x;
    const int lane = tid & 63;
    const int wid  = tid >> 6;   // 16 waves

    const float4* l4 = (const float4*)losses;   // NROWS/4 = 4096 float4
    float s = 0.0f;
    #pragma unroll
    for (int j = 0; j < 4; ++j) {
        float4 v = l4[tid + 1024 * j];
        s += v.x + v.y + v.z + v.w;
    }
    #pragma unroll
    for (int m = 1; m < 64; m <<= 1) s += __shfl_xor(s, m, 64);

    __shared__ float sm[16];
    if (lane == 0) sm[wid] = s;
    __syncthreads();
    if (tid == 0) {
        float total = 0.f;
        #pragma unroll
        for (int w = 0; w < 16; ++w) total += sm[w];
        out[0] = total / (2.0f * (float)NROWS);
    }
}

extern "C" void kernel_launch(void* const* d_in, const int* in_sizes, int n_in,
                              void* d_out, int out_size, void* d_ws, size_t ws_size,
                              hipStream_t stream) {
    const float* emb = (const float*)d_in[0];
    // d_in[1] = labels (unused by the loss itself)
    const int* pos = (const int*)d_in[2];
    const int* neg = (const int*)d_in[3];

    float* losses = (float*)d_ws;          // NROWS floats of scratch
    float* out    = (float*)d_out;

    row_loss_kernel<<<NROWS / 4, 256, 0, stream>>>(emb, pos, neg, losses);
    final_reduce_kernel<<<1, 1024, 0, stream>>>(losses, out);
}